// Round 1
// baseline (872.077 us; speedup 1.0000x reference)
//
#include <hip/hip_runtime.h>
#include <math.h>

#define P 16384               // 128*128 pixels
#define SCALEF 0.08838834764831845f  // 128^-0.5

// ---------------------------------------------------------------------------
// Generic 1x1 conv as GEMM: out[oc][p] = sum_ic w[oc][ic]*in[ic][p] (+bias)
// tile 64 oc x 128 p, block 256, BK=16
// ---------------------------------------------------------------------------
__global__ __launch_bounds__(256) void k_conv1x1(
    const float* __restrict__ in, const float* __restrict__ w,
    const float* __restrict__ bias, float* __restrict__ out, int IC)
{
  __shared__ float aL[16][64];    // [kk][oc]
  __shared__ float bL[16][128];   // [kk][pp]
  const int p0  = blockIdx.x * 128;
  const int oc0 = blockIdx.y * 64;
  const int tid = threadIdx.x;
  const int pcol = tid & 31;      // 4 pixels each
  const int orow = tid >> 5;      // 8 ocs each
  float acc[8][4] = {};

  for (int k0 = 0; k0 < IC; k0 += 16) {
    // stage A (weights): 64x16 = 1024 elems, 4/thread
    {
      int e = tid * 4;
      int oc_l = e >> 4;
      int kk = e & 15;                 // in {0,4,8,12}
      float4 wv = *(const float4*)&w[(oc0 + oc_l) * IC + k0 + kk];
      aL[kk+0][oc_l] = wv.x; aL[kk+1][oc_l] = wv.y;
      aL[kk+2][oc_l] = wv.z; aL[kk+3][oc_l] = wv.w;
    }
    // stage B (input): 16x128 = 2048 elems, 2 float4/thread
    {
      #pragma unroll
      for (int q = 0; q < 2; ++q) {
        int e4 = tid * 2 + q;          // 0..511
        int kk = e4 >> 5;
        int p4 = e4 & 31;
        float4 bv = *(const float4*)&in[(k0 + kk) * P + p0 + p4 * 4];
        *(float4*)&bL[kk][p4 * 4] = bv;
      }
    }
    __syncthreads();
    #pragma unroll
    for (int kk = 0; kk < 16; ++kk) {
      float4 bv = *(const float4*)&bL[kk][pcol * 4];
      float a[8];
      #pragma unroll
      for (int i = 0; i < 8; ++i) a[i] = aL[kk][orow * 8 + i];
      #pragma unroll
      for (int i = 0; i < 8; ++i) {
        acc[i][0] += a[i] * bv.x; acc[i][1] += a[i] * bv.y;
        acc[i][2] += a[i] * bv.z; acc[i][3] += a[i] * bv.w;
      }
    }
    __syncthreads();
  }
  #pragma unroll
  for (int i = 0; i < 8; ++i) {
    int oc = oc0 + orow * 8 + i;
    float bb = bias ? bias[oc] : 0.f;
    float4 o;
    o.x = acc[i][0] + bb; o.y = acc[i][1] + bb;
    o.z = acc[i][2] + bb; o.w = acc[i][3] + bb;
    *(float4*)&out[oc * P + p0 + pcol * 4] = o;
  }
}

// ---------------------------------------------------------------------------
// Depthwise KxK conv, pad K/2. grid (P/256, 384), block 256
// ---------------------------------------------------------------------------
template<int K>
__global__ __launch_bounds__(256) void k_dw(
    const float* __restrict__ in, const float* __restrict__ w,
    float* __restrict__ out)
{
  const int c = blockIdx.y;
  const int p = blockIdx.x * 256 + threadIdx.x;
  const int y = p >> 7, x = p & 127;
  const float* wp = &w[c * K * K];
  const float* ip = &in[c * P];
  float acc = 0.f;
  #pragma unroll
  for (int dy = 0; dy < K; ++dy) {
    int yy = y + dy - K / 2;
    if (yy < 0 || yy > 127) continue;
    #pragma unroll
    for (int dx = 0; dx < K; ++dx) {
      int xx = x + dx - K / 2;
      if (xx < 0 || xx > 127) continue;
      acc += wp[dy * K + dx] * ip[yy * 128 + xx];
    }
  }
  out[c * P + p] = acc;
}

// ---------------------------------------------------------------------------
// Grouped pointwise (12 groups of 32->32). grid (P/256, 12), block 256
// ---------------------------------------------------------------------------
__global__ __launch_bounds__(256) void k_pw(
    const float* __restrict__ in, const float* __restrict__ w,
    float* __restrict__ out)
{
  const int g = blockIdx.y;
  const int p = blockIdx.x * 256 + threadIdx.x;
  __shared__ float wL[1024];
  for (int e = threadIdx.x; e < 1024; e += 256) wL[e] = w[g * 1024 + e];
  __syncthreads();
  float r[32];
  #pragma unroll
  for (int i = 0; i < 32; ++i) r[i] = in[(g * 32 + i) * P + p];
  #pragma unroll
  for (int o = 0; o < 32; ++o) {
    float acc = 0.f;
    #pragma unroll
    for (int i = 0; i < 32; ++i) acc += wL[o * 32 + i] * r[i];
    out[(g * 32 + o) * P + p] = acc;
  }
}

// ---------------------------------------------------------------------------
// Window max of q (ch 0..127) and k (ch 128..255). grid (64, 3), block 256
// thread = channel; each scans its window's 256 pixels.
// ---------------------------------------------------------------------------
__global__ __launch_bounds__(256) void k_winmax(
    const float* __restrict__ e0, const float* __restrict__ e1,
    const float* __restrict__ e2, float* __restrict__ qwin,
    float* __restrict__ kwin)
{
  const int b = blockIdx.y;
  const int wIdx = blockIdx.x;
  const float* e = (b == 0) ? e0 : ((b == 1) ? e1 : e2);
  const int c = threadIdx.x;          // 0..255
  const int wy = wIdx >> 3, wx = wIdx & 7;
  const float* base = &e[c * P + (wy * 16) * 128 + wx * 16];
  float m = -INFINITY;
  for (int iy = 0; iy < 16; ++iy) {
    const float4* row = (const float4*)&base[iy * 128];
    #pragma unroll
    for (int j = 0; j < 4; ++j) {
      float4 v = row[j];
      m = fmaxf(m, fmaxf(fmaxf(v.x, v.y), fmaxf(v.z, v.w)));
    }
  }
  if (c < 128) qwin[(b * 64 + wIdx) * 128 + c] = m;
  else         kwin[(b * 64 + wIdx) * 128 + (c - 128)] = m;
}

// ---------------------------------------------------------------------------
// Window logits (64x64) + top-4 (ties -> lowest index, like jax.lax.top_k)
// grid 3 (branch), block 64 (thread = query window)
// ---------------------------------------------------------------------------
__global__ __launch_bounds__(64) void k_topk(
    const float* __restrict__ qwin, const float* __restrict__ kwin,
    int* __restrict__ ridx)
{
  const int b = blockIdx.x;
  const int i = threadIdx.x;
  __shared__ float lg[64][65];
  float4 qr[32];
  const float4* q4 = (const float4*)&qwin[(b * 64 + i) * 128];
  #pragma unroll
  for (int t = 0; t < 32; ++t) qr[t] = q4[t];
  for (int j = 0; j < 64; ++j) {
    const float4* k4 = (const float4*)&kwin[(b * 64 + j) * 128];
    float acc = 0.f;
    #pragma unroll
    for (int t = 0; t < 32; ++t) {
      float4 kv = k4[t];
      acc += qr[t].x * kv.x + qr[t].y * kv.y + qr[t].z * kv.z + qr[t].w * kv.w;
    }
    lg[i][j] = acc * SCALEF;
  }
  unsigned long long mask = 0ull;
  for (int r = 0; r < 4; ++r) {
    float best = -INFINITY; int bj = 0;
    for (int j = 0; j < 64; ++j) {
      if ((mask >> j) & 1ull) continue;
      float v = lg[i][j];
      if (v > best) { best = v; bj = j; }   // strict > keeps lowest index on ties
    }
    mask |= (1ull << bj);
    ridx[(b * 64 + i) * 4 + r] = bj;
  }
}

// ---------------------------------------------------------------------------
// Attention: block = (window, head, branch); 256 threads = 256 queries.
// Online softmax over 4 selected windows (1024 keys), K/V staged in LDS in
// 128-key chunks (rows padded to 36 floats -> 16B-aligned float4 reads).
// Writes channel-major spatial output: attnch[b*128 + h*32+d][hw]
// ---------------------------------------------------------------------------
__global__ __launch_bounds__(256) void k_attn(
    const float* __restrict__ e0, const float* __restrict__ e1,
    const float* __restrict__ e2, const int* __restrict__ ridx,
    float* __restrict__ attnch)
{
  const int b = blockIdx.z;
  const int h = blockIdx.y;
  const int wIdx = blockIdx.x;
  const float* e = (b == 0) ? e0 : ((b == 1) ? e1 : e2);
  const int s = threadIdx.x;
  const int wy = wIdx >> 3, wx = wIdx & 7;
  const int hw = (wy * 16 + (s >> 4)) * 128 + wx * 16 + (s & 15);

  float q[32];
  #pragma unroll
  for (int d = 0; d < 32; ++d)
    q[d] = e[(h * 32 + d) * P + hw] * SCALEF;

  float m = -INFINITY, l = 0.f;
  float acc[32] = {};

  __shared__ float kL[128 * 36];
  __shared__ float vL[128 * 36];

  for (int r = 0; r < 4; ++r) {
    const int j = ridx[(b * 64 + wIdx) * 4 + r];
    const int jbase = ((j >> 3) * 16) * 128 + (j & 7) * 16;
    for (int half = 0; half < 2; ++half) {
      __syncthreads();
      // stage 128 keys x 32 dims of k and v
      {
        const int tt = threadIdx.x & 127;
        const int dh = threadIdx.x >> 7;        // 0/1
        const int tg = half * 128 + tt;
        const int ghw = jbase + ((tg >> 4) * 128) + (tg & 15);
        #pragma unroll
        for (int dd = 0; dd < 16; ++dd) {
          int d = dd * 2 + dh;
          kL[tt * 36 + d] = e[(128 + h * 32 + d) * P + ghw];
          vL[tt * 36 + d] = e[(256 + h * 32 + d) * P + ghw];
        }
      }
      __syncthreads();
      for (int t = 0; t < 128; ++t) {
        const float4* kp = (const float4*)&kL[t * 36];
        float dot = 0.f;
        #pragma unroll
        for (int c = 0; c < 8; ++c) {
          float4 kv = kp[c];
          dot += q[c*4+0]*kv.x + q[c*4+1]*kv.y + q[c*4+2]*kv.z + q[c*4+3]*kv.w;
        }
        if (dot > m) {                 // rare rescale
          float corr = __expf(m - dot);
          m = dot;
          l *= corr;
          #pragma unroll
          for (int d = 0; d < 32; ++d) acc[d] *= corr;
        }
        float pw = __expf(dot - m);
        l += pw;
        const float4* vp = (const float4*)&vL[t * 36];
        #pragma unroll
        for (int c = 0; c < 8; ++c) {
          float4 vv = vp[c];
          acc[c*4+0] += pw * vv.x; acc[c*4+1] += pw * vv.y;
          acc[c*4+2] += pw * vv.z; acc[c*4+3] += pw * vv.w;
        }
      }
    }
  }
  const float inv = 1.f / l;
  #pragma unroll
  for (int d = 0; d < 32; ++d)
    attnch[(b * 128 + h * 32 + d) * P + hw] = acc[d] * inv;
}

// ---------------------------------------------------------------------------
// LayerNorm over 128 channels per pixel. grid 256, block 64 (thread = pixel)
// ---------------------------------------------------------------------------
__global__ __launch_bounds__(64) void k_ln(
    const float* __restrict__ in, const float* __restrict__ g,
    const float* __restrict__ bta, float* __restrict__ out)
{
  const int p = blockIdx.x * 64 + threadIdx.x;
  float sum = 0.f;
  for (int c = 0; c < 128; ++c) sum += in[c * P + p];
  const float mu = sum * (1.f / 128.f);
  float s2 = 0.f;
  for (int c = 0; c < 128; ++c) { float d = in[c * P + p] - mu; s2 += d * d; }
  const float rs = rsqrtf(s2 * (1.f / 128.f) + 1e-5f);
  for (int c = 0; c < 128; ++c)
    out[c * P + p] = (in[c * P + p] - mu) * rs * g[c] + bta[c];
}

// ---------------------------------------------------------------------------
extern "C" void kernel_launch(void* const* d_in, const int* in_sizes, int n_in,
                              void* d_out, int out_size, void* d_ws, size_t ws_size,
                              hipStream_t stream)
{
  (void)in_sizes; (void)n_in; (void)out_size;
  const float* x      = (const float*)d_in[0];
  const float* qkv2_w = (const float*)d_in[1];
  const float* dw3_w  = (const float*)d_in[2];
  const float* pw3_w  = (const float*)d_in[3];
  const float* dw5_w  = (const float*)d_in[4];
  const float* pw5_w  = (const float*)d_in[5];
  const float* mlp_w  = (const float*)d_in[6];
  const float* mlp_b  = (const float*)d_in[7];
  const float* proj_w = (const float*)d_in[8];
  const float* ln_g   = (const float*)d_in[9];
  const float* ln_b   = (const float*)d_in[10];

  float* ws = (float*)d_ws;
  // workspace layout (floats); aliasing: dwt->attnch, qkv->proj-out
  const size_t CH = (size_t)384 * P;          // 6291456
  float* qkv    = ws;                          // later: proj out
  float* dwt    = ws + CH;                     // later: attnch (3*128 ch)
  float* y3     = ws + 2 * CH;
  float* y5     = ws + 3 * CH;
  float* cat    = ws + 4 * CH;
  float* qwin   = ws + 5 * CH;                 // 3*64*128
  float* kwin   = qwin + 3 * 64 * 128;
  int*   ridx   = (int*)(kwin + 3 * 64 * 128); // 3*64*4 ints
  float* attnch = dwt;
  float* projo  = qkv;
  (void)ws_size; // requires ~126 MB of workspace

  // 1. qkv = conv1x1(x)
  k_conv1x1<<<dim3(128, 6), 256, 0, stream>>>(x, qkv2_w, nullptr, qkv, 128);
  // 2-5. two dw+pw branches
  k_dw<3><<<dim3(64, 384), 256, 0, stream>>>(qkv, dw3_w, dwt);
  k_pw<<<dim3(64, 12), 256, 0, stream>>>(dwt, pw3_w, y3);
  k_dw<5><<<dim3(64, 384), 256, 0, stream>>>(qkv, dw5_w, dwt);
  k_pw<<<dim3(64, 12), 256, 0, stream>>>(dwt, pw5_w, y5);
  // 6. window maxes (all 3 branches)
  k_winmax<<<dim3(64, 3), 256, 0, stream>>>(qkv, y3, y5, qwin, kwin);
  // 7. logits + top-4
  k_topk<<<dim3(3), 64, 0, stream>>>(qwin, kwin, ridx);
  // 8. attention (writes channel-major spatial layout)
  k_attn<<<dim3(64, 4, 3), 256, 0, stream>>>(qkv, y3, y5, ridx, attnch);
  // 9. mlp per branch -> concat buffer
  for (int b = 0; b < 3; ++b)
    k_conv1x1<<<dim3(128, 2), 256, 0, stream>>>(attnch + (size_t)b * 128 * P,
                                                mlp_w, mlp_b,
                                                cat + (size_t)b * 128 * P, 128);
  // 10. proj
  k_conv1x1<<<dim3(128, 2), 256, 0, stream>>>(cat, proj_w, nullptr, projo, 384);
  // 11. layernorm -> d_out
  k_ln<<<dim3(256), 64, 0, stream>>>(projo, ln_g, ln_b, (float*)d_out);
}

// Round 2
// 560.781 us; speedup vs baseline: 1.5551x; 1.5551x over previous
//
#include <hip/hip_runtime.h>
#include <math.h>

#define P 16384               // 128*128 pixels
#define SCALEF 0.08838834764831845f  // 128^-0.5

typedef short bf16x8 __attribute__((ext_vector_type(8)));
typedef float f32x4 __attribute__((ext_vector_type(4)));

__device__ __forceinline__ unsigned short f2bf(float x) {
  union { float f; unsigned int u; } v; v.f = x;
  unsigned int r = v.u + 0x7fffu + ((v.u >> 16) & 1u);  // RNE
  return (unsigned short)(r >> 16);
}
__device__ __forceinline__ unsigned int packbf(float a, float b) {
  return (unsigned int)f2bf(a) | ((unsigned int)f2bf(b) << 16);
}

// ---------------------------------------------------------------------------
// Generic 1x1 conv as GEMM: out[oc][p] = sum_ic w[oc][ic]*in[ic][p] (+bias)
// ---------------------------------------------------------------------------
__global__ __launch_bounds__(256) void k_conv1x1(
    const float* __restrict__ in, const float* __restrict__ w,
    const float* __restrict__ bias, float* __restrict__ out, int IC)
{
  __shared__ float aL[16][64];    // [kk][oc]
  __shared__ float bL[16][128];   // [kk][pp]
  const int p0  = blockIdx.x * 128;
  const int oc0 = blockIdx.y * 64;
  const int tid = threadIdx.x;
  const int pcol = tid & 31;
  const int orow = tid >> 5;
  float acc[8][4] = {};

  for (int k0 = 0; k0 < IC; k0 += 16) {
    {
      int e = tid * 4;
      int oc_l = e >> 4;
      int kk = e & 15;
      float4 wv = *(const float4*)&w[(oc0 + oc_l) * IC + k0 + kk];
      aL[kk+0][oc_l] = wv.x; aL[kk+1][oc_l] = wv.y;
      aL[kk+2][oc_l] = wv.z; aL[kk+3][oc_l] = wv.w;
    }
    {
      #pragma unroll
      for (int q = 0; q < 2; ++q) {
        int e4 = tid * 2 + q;
        int kk = e4 >> 5;
        int p4 = e4 & 31;
        float4 bv = *(const float4*)&in[(k0 + kk) * P + p0 + p4 * 4];
        *(float4*)&bL[kk][p4 * 4] = bv;
      }
    }
    __syncthreads();
    #pragma unroll
    for (int kk = 0; kk < 16; ++kk) {
      float4 bv = *(const float4*)&bL[kk][pcol * 4];
      float a[8];
      #pragma unroll
      for (int i = 0; i < 8; ++i) a[i] = aL[kk][orow * 8 + i];
      #pragma unroll
      for (int i = 0; i < 8; ++i) {
        acc[i][0] += a[i] * bv.x; acc[i][1] += a[i] * bv.y;
        acc[i][2] += a[i] * bv.z; acc[i][3] += a[i] * bv.w;
      }
    }
    __syncthreads();
  }
  #pragma unroll
  for (int i = 0; i < 8; ++i) {
    int oc = oc0 + orow * 8 + i;
    float bb = bias ? bias[oc] : 0.f;
    float4 o;
    o.x = acc[i][0] + bb; o.y = acc[i][1] + bb;
    o.z = acc[i][2] + bb; o.w = acc[i][3] + bb;
    *(float4*)&out[oc * P + p0 + pcol * 4] = o;
  }
}

// ---------------------------------------------------------------------------
// Depthwise KxK conv
// ---------------------------------------------------------------------------
template<int K>
__global__ __launch_bounds__(256) void k_dw(
    const float* __restrict__ in, const float* __restrict__ w,
    float* __restrict__ out)
{
  const int c = blockIdx.y;
  const int p = blockIdx.x * 256 + threadIdx.x;
  const int y = p >> 7, x = p & 127;
  const float* wp = &w[c * K * K];
  const float* ip = &in[c * P];
  float acc = 0.f;
  #pragma unroll
  for (int dy = 0; dy < K; ++dy) {
    int yy = y + dy - K / 2;
    if (yy < 0 || yy > 127) continue;
    #pragma unroll
    for (int dx = 0; dx < K; ++dx) {
      int xx = x + dx - K / 2;
      if (xx < 0 || xx > 127) continue;
      acc += wp[dy * K + dx] * ip[yy * 128 + xx];
    }
  }
  out[c * P + p] = acc;
}

// ---------------------------------------------------------------------------
// Grouped pointwise (12 groups of 32->32)
// ---------------------------------------------------------------------------
__global__ __launch_bounds__(256) void k_pw(
    const float* __restrict__ in, const float* __restrict__ w,
    float* __restrict__ out)
{
  const int g = blockIdx.y;
  const int p = blockIdx.x * 256 + threadIdx.x;
  __shared__ float wL[1024];
  for (int e = threadIdx.x; e < 1024; e += 256) wL[e] = w[g * 1024 + e];
  __syncthreads();
  float r[32];
  #pragma unroll
  for (int i = 0; i < 32; ++i) r[i] = in[(g * 32 + i) * P + p];
  #pragma unroll
  for (int o = 0; o < 32; ++o) {
    float acc = 0.f;
    #pragma unroll
    for (int i = 0; i < 32; ++i) acc += wL[o * 32 + i] * r[i];
    out[(g * 32 + o) * P + p] = acc;
  }
}

// ---------------------------------------------------------------------------
// Window max of q (ch 0..127) and k (ch 128..255)
// ---------------------------------------------------------------------------
__global__ __launch_bounds__(256) void k_winmax(
    const float* __restrict__ e0, const float* __restrict__ e1,
    const float* __restrict__ e2, float* __restrict__ qwin,
    float* __restrict__ kwin)
{
  const int b = blockIdx.y;
  const int wIdx = blockIdx.x;
  const float* e = (b == 0) ? e0 : ((b == 1) ? e1 : e2);
  const int c = threadIdx.x;
  const int wy = wIdx >> 3, wx = wIdx & 7;
  const float* base = &e[c * P + (wy * 16) * 128 + wx * 16];
  float m = -INFINITY;
  for (int iy = 0; iy < 16; ++iy) {
    const float4* row = (const float4*)&base[iy * 128];
    #pragma unroll
    for (int j = 0; j < 4; ++j) {
      float4 v = row[j];
      m = fmaxf(m, fmaxf(fmaxf(v.x, v.y), fmaxf(v.z, v.w)));
    }
  }
  if (c < 128) qwin[(b * 64 + wIdx) * 128 + c] = m;
  else         kwin[(b * 64 + wIdx) * 128 + (c - 128)] = m;
}

// ---------------------------------------------------------------------------
// Window logits (64x64) + top-4 (ties -> lowest index) — exact fp32
// ---------------------------------------------------------------------------
__global__ __launch_bounds__(64) void k_topk(
    const float* __restrict__ qwin, const float* __restrict__ kwin,
    int* __restrict__ ridx)
{
  const int b = blockIdx.x;
  const int i = threadIdx.x;
  __shared__ float lg[64][65];
  float4 qr[32];
  const float4* q4 = (const float4*)&qwin[(b * 64 + i) * 128];
  #pragma unroll
  for (int t = 0; t < 32; ++t) qr[t] = q4[t];
  for (int j = 0; j < 64; ++j) {
    const float4* k4 = (const float4*)&kwin[(b * 64 + j) * 128];
    float acc = 0.f;
    #pragma unroll
    for (int t = 0; t < 32; ++t) {
      float4 kv = k4[t];
      acc += qr[t].x * kv.x + qr[t].y * kv.y + qr[t].z * kv.z + qr[t].w * kv.w;
    }
    lg[i][j] = acc * SCALEF;
  }
  unsigned long long mask = 0ull;
  for (int r = 0; r < 4; ++r) {
    float best = -INFINITY; int bj = 0;
    for (int j = 0; j < 64; ++j) {
      if ((mask >> j) & 1ull) continue;
      float v = lg[i][j];
      if (v > best) { best = v; bj = j; }
    }
    mask |= (1ull << bj);
    ridx[(b * 64 + i) * 4 + r] = bj;
  }
}

// ---------------------------------------------------------------------------
// MFMA flash attention. block = (window, head, branch); 4 waves x 64 queries.
// Swapped QK^T (mfma(K,Q)) with permuted A-rows so P lands in-lane in exactly
// the B-fragment layout PV needs. K[256][32] + V^T[32][256] staged in LDS
// (XOR-swizzled, frag reads at bank-volume floor). One rescale per window.
// ---------------------------------------------------------------------------
__global__ __launch_bounds__(256) void k_attn_mfma(
    const float* __restrict__ e0, const float* __restrict__ e1,
    const float* __restrict__ e2, const int* __restrict__ ridx,
    float* __restrict__ attnch)
{
  const int b = blockIdx.z, h = blockIdx.y, w = blockIdx.x;
  const float* e = (b == 0) ? e0 : ((b == 1) ? e1 : e2);
  const float* eQ = e + (size_t)(h * 32) * P;
  const float* eK = e + (size_t)(128 + h * 32) * P;
  const float* eV = e + (size_t)(256 + h * 32) * P;
  const int wy = w >> 3, wx = w & 7;
  const int tid = threadIdx.x;
  const int wv = tid >> 6, lane = tid & 63;
  const int qi = lane & 15, g = lane >> 4;

  __shared__ __align__(16) unsigned int   kS4[256 * 16]; // [key][32 bf16] swz
  __shared__ __align__(16) unsigned short vS[32 * 256];  // [d][key] swz

  // Q fragments: lane (qi,g) holds Q[q = wv*64+s*16+qi][d = 8g..8g+7] * SCALE
  bf16x8 qv[4];
  #pragma unroll
  for (int s = 0; s < 4; ++s) {
    const int hwq = (wy * 16 + wv * 4 + s) * 128 + wx * 16 + qi;
    union { bf16x8 v; unsigned short u[8]; } tmp;
    #pragma unroll
    for (int i = 0; i < 8; ++i)
      tmp.u[i] = f2bf(eQ[(size_t)(g * 8 + i) * P + hwq] * SCALEF);
    qv[s] = tmp.v;
  }

  const f32x4 fz = {0.f, 0.f, 0.f, 0.f};
  float m[4], l[4];
  f32x4 acc[4][2];
  #pragma unroll
  for (int s = 0; s < 4; ++s) {
    m[s] = -3.0e38f; l[s] = 0.f; acc[s][0] = fz; acc[s][1] = fz;
  }

  for (int r = 0; r < 4; ++r) {
    const int j = ridx[(b * 64 + w) * 4 + r];
    const int jbase = ((j >> 3) * 16) * 128 + (j & 7) * 16;
    const int hwt = jbase + (tid >> 4) * 128 + (tid & 15);
    __syncthreads();
    // stage K: thread = key, 16 packed u32 (d-pairs), swizzled cols
    #pragma unroll
    for (int dd = 0; dd < 16; ++dd) {
      float v0 = eK[(size_t)(2 * dd) * P + hwt];
      float v1 = eK[(size_t)(2 * dd + 1) * P + hwt];
      kS4[tid * 16 + (dd ^ ((tid & 3) << 2))] = packbf(v0, v1);
    }
    // stage V^T: [d][key], row-XOR swizzle; consecutive tid -> consecutive u16
    #pragma unroll
    for (int d = 0; d < 32; ++d) {
      float v = eV[(size_t)d * P + hwt];
      vS[(unsigned)((d * 256 + tid) ^ ((d & 7) << 3))] = f2bf(v);
    }
    __syncthreads();

    const bf16x8* kp = (const bf16x8*)kS4;
    #pragma unroll
    for (int s = 0; s < 4; ++s) {
      // QK^T: 16 MFMAs; A-row j holds key 32c + 8*(j>>2) + 4u + (j&3)
      f32x4 sc[8][2];
      #pragma unroll
      for (int c = 0; c < 8; ++c) {
        #pragma unroll
        for (int u = 0; u < 2; ++u) {
          const int key = 32 * c + 8 * (qi >> 2) + 4 * u + (qi & 3);
          const bf16x8 ka = kp[key * 4 + (g ^ (qi & 3))];
          sc[c][u] = __builtin_amdgcn_mfma_f32_16x16x32_bf16(ka, qv[s], fz, 0, 0, 0);
        }
      }
      // lane's scores are keys 32c + 8g + 4u + t for query (s,qi)
      float wmax = -3.0e38f;
      #pragma unroll
      for (int c = 0; c < 8; ++c)
        #pragma unroll
        for (int u = 0; u < 2; ++u)
          #pragma unroll
          for (int t = 0; t < 4; ++t)
            wmax = fmaxf(wmax, sc[c][u][t]);
      wmax = fmaxf(wmax, __shfl_xor(wmax, 16, 64));
      wmax = fmaxf(wmax, __shfl_xor(wmax, 32, 64));
      const float mnew = fmaxf(m[s], wmax);
      const float corr = __expf(m[s] - mnew);

      float psum = 0.f;
      unsigned int pk[8][4];
      #pragma unroll
      for (int c = 0; c < 8; ++c) {
        #pragma unroll
        for (int u = 0; u < 2; ++u) {
          const float p0 = __expf(sc[c][u][0] - mnew);
          const float p1 = __expf(sc[c][u][1] - mnew);
          const float p2 = __expf(sc[c][u][2] - mnew);
          const float p3 = __expf(sc[c][u][3] - mnew);
          psum += (p0 + p1) + (p2 + p3);
          pk[c][2 * u + 0] = packbf(p0, p1);
          pk[c][2 * u + 1] = packbf(p2, p3);
        }
      }
      psum += __shfl_xor(psum, 16, 64);
      psum += __shfl_xor(psum, 32, 64);
      l[s] = l[s] * corr + psum;
      m[s] = mnew;
      acc[s][0] *= corr;
      acc[s][1] *= corr;

      // PV: O^T[dtile][q] += V^T-frag x P-frag (P already in-lane, in order)
      #pragma unroll
      for (int c = 0; c < 8; ++c) {
        union { unsigned int u4[4]; bf16x8 v; } pb;
        pb.u4[0] = pk[c][0]; pb.u4[1] = pk[c][1];
        pb.u4[2] = pk[c][2]; pb.u4[3] = pk[c][3];
        #pragma unroll
        for (int dt = 0; dt < 2; ++dt) {
          const int d0 = dt * 16 + qi;
          const bf16x8 va = *(const bf16x8*)&vS[
              (unsigned)((d0 * 256 + 32 * c + 8 * g) ^ ((d0 & 7) << 3))];
          acc[s][dt] = __builtin_amdgcn_mfma_f32_16x16x32_bf16(va, pb.v, acc[s][dt], 0, 0, 0);
        }
      }
    }
  }

  // epilogue: lane (qi,g) holds O^T[d = dt*16+4g+t][q = s*16+qi]
  #pragma unroll
  for (int s = 0; s < 4; ++s) {
    const float inv = 1.f / l[s];
    const int hwq = (wy * 16 + wv * 4 + s) * 128 + wx * 16 + qi;
    #pragma unroll
    for (int dt = 0; dt < 2; ++dt)
      #pragma unroll
      for (int t = 0; t < 4; ++t) {
        const int d = dt * 16 + 4 * g + t;
        attnch[(size_t)(b * 128 + h * 32 + d) * P + hwq] = acc[s][dt][t] * inv;
      }
  }
}

// ---------------------------------------------------------------------------
// LayerNorm over 128 channels per pixel
// ---------------------------------------------------------------------------
__global__ __launch_bounds__(64) void k_ln(
    const float* __restrict__ in, const float* __restrict__ g,
    const float* __restrict__ bta, float* __restrict__ out)
{
  const int p = blockIdx.x * 64 + threadIdx.x;
  float sum = 0.f;
  for (int c = 0; c < 128; ++c) sum += in[c * P + p];
  const float mu = sum * (1.f / 128.f);
  float s2 = 0.f;
  for (int c = 0; c < 128; ++c) { float d = in[c * P + p] - mu; s2 += d * d; }
  const float rs = rsqrtf(s2 * (1.f / 128.f) + 1e-5f);
  for (int c = 0; c < 128; ++c)
    out[c * P + p] = (in[c * P + p] - mu) * rs * g[c] + bta[c];
}

// ---------------------------------------------------------------------------
extern "C" void kernel_launch(void* const* d_in, const int* in_sizes, int n_in,
                              void* d_out, int out_size, void* d_ws, size_t ws_size,
                              hipStream_t stream)
{
  (void)in_sizes; (void)n_in; (void)out_size;
  const float* x      = (const float*)d_in[0];
  const float* qkv2_w = (const float*)d_in[1];
  const float* dw3_w  = (const float*)d_in[2];
  const float* pw3_w  = (const float*)d_in[3];
  const float* dw5_w  = (const float*)d_in[4];
  const float* pw5_w  = (const float*)d_in[5];
  const float* mlp_w  = (const float*)d_in[6];
  const float* mlp_b  = (const float*)d_in[7];
  const float* proj_w = (const float*)d_in[8];
  const float* ln_g   = (const float*)d_in[9];
  const float* ln_b   = (const float*)d_in[10];

  float* ws = (float*)d_ws;
  const size_t CH = (size_t)384 * P;
  float* qkv    = ws;                          // later: proj out
  float* dwt    = ws + CH;                     // later: attnch
  float* y3     = ws + 2 * CH;
  float* y5     = ws + 3 * CH;
  float* cat    = ws + 4 * CH;
  float* qwin   = ws + 5 * CH;
  float* kwin   = qwin + 3 * 64 * 128;
  int*   ridx   = (int*)(kwin + 3 * 64 * 128);
  float* attnch = dwt;
  float* projo  = qkv;
  (void)ws_size;

  k_conv1x1<<<dim3(128, 6), 256, 0, stream>>>(x, qkv2_w, nullptr, qkv, 128);
  k_dw<3><<<dim3(64, 384), 256, 0, stream>>>(qkv, dw3_w, dwt);
  k_pw<<<dim3(64, 12), 256, 0, stream>>>(dwt, pw3_w, y3);
  k_dw<5><<<dim3(64, 384), 256, 0, stream>>>(qkv, dw5_w, dwt);
  k_pw<<<dim3(64, 12), 256, 0, stream>>>(dwt, pw5_w, y5);
  k_winmax<<<dim3(64, 3), 256, 0, stream>>>(qkv, y3, y5, qwin, kwin);
  k_topk<<<dim3(3), 64, 0, stream>>>(qwin, kwin, ridx);
  k_attn_mfma<<<dim3(64, 4, 3), 256, 0, stream>>>(qkv, y3, y5, ridx, attnch);
  for (int b = 0; b < 3; ++b)
    k_conv1x1<<<dim3(128, 2), 256, 0, stream>>>(attnch + (size_t)b * 128 * P,
                                                mlp_w, mlp_b,
                                                cat + (size_t)b * 128 * P, 128);
  k_conv1x1<<<dim3(128, 2), 256, 0, stream>>>(cat, proj_w, nullptr, projo, 384);
  k_ln<<<dim3(256), 64, 0, stream>>>(projo, ln_g, ln_b, (float*)d_out);
}